// Round 1
// baseline (5084.861 us; speedup 1.0000x reference)
//
#include <hip/hip_runtime.h>
#include <stdint.h>

// ---------- types / helpers ----------
typedef __bf16 bf16x8 __attribute__((ext_vector_type(8)));
typedef float  f32x4  __attribute__((ext_vector_type(4)));

#define DEV static __device__ __forceinline__

DEV float b2f(unsigned short u) {
    unsigned int v = ((unsigned int)u) << 16;
    return __builtin_bit_cast(float, v);
}
DEV unsigned short f2b(float f) {  // RNE
    unsigned int u = __builtin_bit_cast(unsigned int, f);
    u += 0x7fffu + ((u >> 16) & 1u);
    return (unsigned short)(u >> 16);
}
DEV void gload_lds16(const void* g, void* l) {
    __builtin_amdgcn_global_load_lds(
        (__attribute__((address_space(1))) void*)(void*)g,
        (__attribute__((address_space(3))) void*)l, 16, 0, 0);
}

// ---------- elementwise f32 -> bf16 ----------
__global__ void cvt_f32_bf16(const float* __restrict__ in,
                             unsigned short* __restrict__ out, int n4) {
    int i = blockIdx.x * 256 + threadIdx.x;
    if (i < n4) {
        float4 v = ((const float4*)in)[i];
        ushort4 o;
        o.x = f2b(v.x); o.y = f2b(v.y); o.z = f2b(v.z); o.w = f2b(v.w);
        ((ushort4*)out)[i] = o;
    }
}

// ---------- transpose + convert: in[K][N] f32 -> out[N][K] bf16 ----------
__global__ void transpose_cvt(const float* __restrict__ in,
                              unsigned short* __restrict__ out, int K, int N) {
    __shared__ float tile[32][33];
    int nb = blockIdx.x, kb = blockIdx.y;
    int tx = threadIdx.x, ty = threadIdx.y;  // 32 x 8
#pragma unroll
    for (int i = 0; i < 4; ++i) {
        int k = kb * 32 + ty + i * 8;
        int n = nb * 32 + tx;
        tile[ty + i * 8][tx] = in[(size_t)k * N + n];
    }
    __syncthreads();
#pragma unroll
    for (int i = 0; i < 4; ++i) {
        int n = nb * 32 + ty + i * 8;
        int k = kb * 32 + tx;
        out[(size_t)n * K + k] = f2b(tile[tx][ty + i * 8]);
    }
}

// ---------- GEMM: C[M,N] = A[M,K](bf16) * BT[N,K](bf16)^T + bias ----------
// EPI: 0 = store f32, 1 = store bf16, 2 = relu+store bf16, 3 = f32 += (residual)
template <int EPI>
__global__ __launch_bounds__(256, 2)
void gemm_bt(const unsigned short* __restrict__ A,
             const unsigned short* __restrict__ BT,
             const float* __restrict__ bias,
             void* __restrict__ Cout, int M, int N, int K) {
    __shared__ alignas(16) unsigned short As[128 * 32];
    __shared__ alignas(16) unsigned short Bs[128 * 32];

    const int tid = threadIdx.x;
    const int lane = tid & 63;
    const int w = tid >> 6;
    const int wr = w >> 1, wc = w & 1;
    const int bm = blockIdx.x, bn = blockIdx.y;

    f32x4 acc[4][4];
#pragma unroll
    for (int i = 0; i < 4; ++i)
#pragma unroll
        for (int j = 0; j < 4; ++j)
#pragma unroll
            for (int r = 0; r < 4; ++r) acc[i][j][r] = 0.f;

    // staging: 8KB tile = 8 chunks of 1024B; wave w does chunks w and w+4.
    const int off0 = (w)*1024 + lane * 16;
    const int off1 = (w + 4) * 1024 + lane * 16;
    const int r0 = off0 >> 6, c0 = off0 & 63;   // tiles are [128 rows][64B]
    const int r1 = off1 >> 6, c1 = off1 & 63;

    const char* Ab0 = (const char*)A + ((size_t)(bm * 128 + r0) * K) * 2 + c0;
    const char* Ab1 = (const char*)A + ((size_t)(bm * 128 + r1) * K) * 2 + c1;
    const char* Bb0 = (const char*)BT + ((size_t)(bn * 128 + r0) * K) * 2 + c0;
    const char* Bb1 = (const char*)BT + ((size_t)(bn * 128 + r1) * K) * 2 + c1;

    char* lA0 = (char*)As + (w)*1024;
    char* lA1 = (char*)As + (w + 4) * 1024;
    char* lB0 = (char*)Bs + (w)*1024;
    char* lB1 = (char*)Bs + (w + 4) * 1024;

    const int rr = lane & 15;
    const int ko = (lane >> 4) * 8;  // k-run start (elems)
    const unsigned short* Ard = As + (wr * 64 + rr) * 32 + ko;
    const unsigned short* Brd = Bs + (wc * 64 + rr) * 32 + ko;

    const int nk = K >> 5;
    for (int kt = 0; kt < nk; ++kt) {
        const size_t kb2 = (size_t)kt * 64;  // byte offset in row
        __syncthreads();
        gload_lds16(Ab0 + kb2, lA0);
        gload_lds16(Ab1 + kb2, lA1);
        gload_lds16(Bb0 + kb2, lB0);
        gload_lds16(Bb1 + kb2, lB1);
        __syncthreads();

        bf16x8 af[4], bg[4];
#pragma unroll
        for (int i = 0; i < 4; ++i) {
            af[i] = *(const bf16x8*)(const void*)(Ard + i * 16 * 32);
            bg[i] = *(const bf16x8*)(const void*)(Brd + i * 16 * 32);
        }
#pragma unroll
        for (int i = 0; i < 4; ++i)
#pragma unroll
            for (int j = 0; j < 4; ++j)
                acc[i][j] = __builtin_amdgcn_mfma_f32_16x16x32_bf16(
                    af[i], bg[j], acc[i][j], 0, 0, 0);
    }

    const int g4 = lane >> 4;
#pragma unroll
    for (int i = 0; i < 4; ++i) {
#pragma unroll
        for (int j = 0; j < 4; ++j) {
            const int col = bn * 128 + wc * 64 + j * 16 + rr;
            const float bv = bias[col];
#pragma unroll
            for (int r = 0; r < 4; ++r) {
                const int row = bm * 128 + wr * 64 + i * 16 + g4 * 4 + r;
                float v = acc[i][j][r] + bv;
                size_t idx = (size_t)row * N + col;
                if (EPI == 0) {
                    ((float*)Cout)[idx] = v;
                } else if (EPI == 1) {
                    ((unsigned short*)Cout)[idx] = f2b(v);
                } else if (EPI == 2) {
                    ((unsigned short*)Cout)[idx] = f2b(v > 0.f ? v : 0.f);
                } else {
                    ((float*)Cout)[idx] += v;
                }
            }
        }
    }
}

// ---------- LayerNorm: x[16384][1024] f32 -> out bf16 ----------
__global__ __launch_bounds__(256)
void ln_kernel(const float* __restrict__ x, const float* __restrict__ g,
               const float* __restrict__ b, unsigned short* __restrict__ out) {
    const int row = blockIdx.x;
    const float* xr = x + (size_t)row * 1024;
    float4 v = ((const float4*)xr)[threadIdx.x];
    float s = v.x + v.y + v.z + v.w;
    float s2 = v.x * v.x + v.y * v.y + v.z * v.z + v.w * v.w;
#pragma unroll
    for (int m = 1; m < 64; m <<= 1) {
        s += __shfl_xor(s, m);
        s2 += __shfl_xor(s2, m);
    }
    __shared__ float red[8];
    int wv = threadIdx.x >> 6, lane = threadIdx.x & 63;
    if (lane == 0) { red[wv] = s; red[4 + wv] = s2; }
    __syncthreads();
    s = red[0] + red[1] + red[2] + red[3];
    s2 = red[4] + red[5] + red[6] + red[7];
    float mu = s * (1.f / 1024.f);
    float var = s2 * (1.f / 1024.f) - mu * mu;
    float rs = rsqrtf(var + 1e-5f);
    float4 gv = ((const float4*)g)[threadIdx.x];
    float4 bv = ((const float4*)b)[threadIdx.x];
    ushort4 o;
    o.x = f2b((v.x - mu) * rs * gv.x + bv.x);
    o.y = f2b((v.y - mu) * rs * gv.y + bv.y);
    o.z = f2b((v.z - mu) * rs * gv.z + bv.z);
    o.w = f2b((v.w - mu) * rs * gv.w + bv.w);
    ((ushort4*)(out + (size_t)row * 1024))[threadIdx.x] = o;
}

// ---------- C8-symmetrized windowed attention ----------
// sym[i,j] = c[(j-i)%8], c[d] = (1/8) sum_i S[i,(i+d)%8]; attn row = perm of
// softmax(c); out[i] = sum_d p[d] * v[(i+d)%8]. One wave per (b,window,head).
__global__ __launch_bounds__(256)
void attn_kernel(const unsigned short* __restrict__ q,
                 const unsigned short* __restrict__ k,
                 const unsigned short* __restrict__ v,
                 unsigned short* __restrict__ ao) {
    const int gid = blockIdx.x * 4 + (threadIdx.x >> 6);  // b*nw*H ids
    const int lane = threadIdx.x & 63;
    const int b = gid >> 12;        // /(256*16)
    const int rem = gid & 4095;
    const int win = rem >> 4;
    const int head = rem & 15;
    const size_t base = ((size_t)(b * 2048 + win * 8)) * 1024 + head * 64 + lane;

    float qf[8], kf[8], vf[8];
#pragma unroll
    for (int i = 0; i < 8; ++i) {
        qf[i] = b2f(q[base + i * 1024]);
        kf[i] = b2f(k[base + i * 1024]);
        vf[i] = b2f(v[base + i * 1024]);
    }
    float c[8];
#pragma unroll
    for (int d = 0; d < 8; ++d) {
        float s = 0.f;
#pragma unroll
        for (int i = 0; i < 8; ++i) s += qf[i] * kf[(i + d) & 7];
        c[d] = s;
    }
#pragma unroll
    for (int m = 1; m < 64; m <<= 1)
#pragma unroll
        for (int d = 0; d < 8; ++d) c[d] += __shfl_xor(c[d], m);
    // scale: /8 (group mean) and /sqrt(64)=8 -> /64
    float mx = -1e30f;
#pragma unroll
    for (int d = 0; d < 8; ++d) { c[d] *= (1.f / 64.f); mx = fmaxf(mx, c[d]); }
    float den = 0.f;
#pragma unroll
    for (int d = 0; d < 8; ++d) { c[d] = expf(c[d] - mx); den += c[d]; }
    float rden = 1.f / den;
#pragma unroll
    for (int i = 0; i < 8; ++i) {
        float o = 0.f;
#pragma unroll
        for (int d = 0; d < 8; ++d) o += c[d] * vf[(i + d) & 7];
        ao[base + i * 1024] = f2b(o * rden);
    }
}

// ---------- mean over sequence (partial sums, atomic) ----------
__global__ void zero_kernel(float* p, int n) {
    int i = blockIdx.x * 256 + threadIdx.x;
    if (i < n) p[i] = 0.f;
}
__global__ void mean_partial(const float* __restrict__ x, float* __restrict__ xsum) {
    int b = blockIdx.x, dc = blockIdx.y, sc = blockIdx.z;
    int d = dc * 256 + threadIdx.x;
    float s = 0.f;
    for (int i = 0; i < 256; ++i)
        s += x[((size_t)(b * 2048 + sc * 256 + i)) * 1024 + d];
    atomicAdd(&xsum[b * 1024 + d], s);
}
// out[b][a] = (xsum[b]/2048) . Wout[:,a] + bout[a]
__global__ void final_gemm(const float* __restrict__ xsum,
                           const float* __restrict__ Wout,
                           const float* __restrict__ bout,
                           float* __restrict__ out) {
    int b = blockIdx.x, a = threadIdx.x;
    float s = 0.f;
    for (int d = 0; d < 1024; ++d) s += xsum[b * 1024 + d] * Wout[d * 256 + a];
    out[b * 256 + a] = s * (1.f / 2048.f) + bout[a];
}

// ---------- launcher ----------
extern "C" void kernel_launch(void* const* d_in, const int* in_sizes, int n_in,
                              void* d_out, int out_size, void* d_ws, size_t ws_size,
                              hipStream_t stream) {
    const float* obs  = (const float*)d_in[0];
    const float* We   = (const float*)d_in[1];
    const float* be   = (const float*)d_in[2];
    const float* Wq   = (const float*)d_in[3];
    const float* bq   = (const float*)d_in[4];
    const float* Wk   = (const float*)d_in[5];
    const float* bk   = (const float*)d_in[6];
    const float* Wv   = (const float*)d_in[7];
    const float* bv   = (const float*)d_in[8];
    const float* Wo   = (const float*)d_in[9];
    const float* bo   = (const float*)d_in[10];
    const float* ln1g = (const float*)d_in[11];
    const float* ln1b = (const float*)d_in[12];
    const float* ln2g = (const float*)d_in[13];
    const float* ln2b = (const float*)d_in[14];
    const float* W1   = (const float*)d_in[15];
    const float* b1   = (const float*)d_in[16];
    const float* W2   = (const float*)d_in[17];
    const float* b2   = (const float*)d_in[18];
    const float* Wout = (const float*)d_in[19];
    const float* bout = (const float*)d_in[20];
    float* out = (float*)d_out;

    char* p = (char*)d_ws;
    float* x = (float*)p;                 p += (size_t)16384 * 1024 * 4;   // 64MB
    unsigned short* h = (unsigned short*)p; p += (size_t)16384 * 1024 * 2; // 32MB
    unsigned short* qb = (unsigned short*)p;                               // union region:
    unsigned short* kb = qb + (size_t)16384 * 1024;
    unsigned short* vb = qb + (size_t)2 * 16384 * 1024;
    unsigned short* aob = qb + (size_t)3 * 16384 * 1024;
    unsigned short* mb = qb;              p += (size_t)16384 * 4096 * 2;   // 128MB
    unsigned short* obsb = (unsigned short*)p; p += (size_t)16384 * 512 * 2;
    unsigned short* WeT = (unsigned short*)p;  p += (size_t)512 * 1024 * 2;
    unsigned short* WqT = (unsigned short*)p;  p += (size_t)1024 * 1024 * 2;
    unsigned short* WkT = (unsigned short*)p;  p += (size_t)1024 * 1024 * 2;
    unsigned short* WvT = (unsigned short*)p;  p += (size_t)1024 * 1024 * 2;
    unsigned short* WoT = (unsigned short*)p;  p += (size_t)1024 * 1024 * 2;
    unsigned short* W1T = (unsigned short*)p;  p += (size_t)1024 * 4096 * 2;
    unsigned short* W2T = (unsigned short*)p;  p += (size_t)4096 * 1024 * 2;
    float* xsum = (float*)p;              p += 8 * 1024 * 4;

    dim3 tb(32, 8);

    // obs -> bf16 (8*2048*512 / 4 = 2097152 float4's)
    cvt_f32_bf16<<<8192, 256, 0, stream>>>(obs, obsb, 2097152);
    // We^T
    transpose_cvt<<<dim3(1024 / 32, 512 / 32), tb, 0, stream>>>(We, WeT, 512, 1024);
    // x = obs @ We + be
    gemm_bt<0><<<dim3(128, 8), 256, 0, stream>>>(obsb, WeT, be, x, 16384, 1024, 512);

    for (int l = 0; l < 8; ++l) {
        const size_t dd = (size_t)l * 1024 * 1024;
        transpose_cvt<<<dim3(32, 32), tb, 0, stream>>>(Wq + dd, WqT, 1024, 1024);
        transpose_cvt<<<dim3(32, 32), tb, 0, stream>>>(Wk + dd, WkT, 1024, 1024);
        transpose_cvt<<<dim3(32, 32), tb, 0, stream>>>(Wv + dd, WvT, 1024, 1024);
        transpose_cvt<<<dim3(32, 32), tb, 0, stream>>>(Wo + dd, WoT, 1024, 1024);
        transpose_cvt<<<dim3(128, 32), tb, 0, stream>>>(W1 + (size_t)l * 1024 * 4096, W1T, 1024, 4096);
        transpose_cvt<<<dim3(32, 128), tb, 0, stream>>>(W2 + (size_t)l * 4096 * 1024, W2T, 4096, 1024);

        ln_kernel<<<16384, 256, 0, stream>>>(x, ln1g + l * 1024, ln1b + l * 1024, h);
        gemm_bt<1><<<dim3(128, 8), 256, 0, stream>>>(h, WqT, bq + l * 1024, qb, 16384, 1024, 1024);
        gemm_bt<1><<<dim3(128, 8), 256, 0, stream>>>(h, WkT, bk + l * 1024, kb, 16384, 1024, 1024);
        gemm_bt<1><<<dim3(128, 8), 256, 0, stream>>>(h, WvT, bv + l * 1024, vb, 16384, 1024, 1024);
        attn_kernel<<<8192, 256, 0, stream>>>(qb, kb, vb, aob);
        gemm_bt<3><<<dim3(128, 8), 256, 0, stream>>>(aob, WoT, bo + l * 1024, x, 16384, 1024, 1024);
        ln_kernel<<<16384, 256, 0, stream>>>(x, ln2g + l * 1024, ln2b + l * 1024, h);
        gemm_bt<2><<<dim3(128, 32), 256, 0, stream>>>(h, W1T, b1 + l * 4096, mb, 16384, 4096, 1024);
        gemm_bt<3><<<dim3(128, 8), 256, 0, stream>>>(mb, W2T, b2 + l * 1024, x, 16384, 1024, 4096);
    }

    zero_kernel<<<32, 256, 0, stream>>>(xsum, 8192);
    mean_partial<<<dim3(8, 4, 8), 256, 0, stream>>>(x, xsum);
    final_gemm<<<8, 256, 0, stream>>>(xsum, Wout, bout, out);
}